// Round 9
// baseline (310.702 us; speedup 1.0000x reference)
//
#include <hip/hip_runtime.h>

typedef __bf16 bf16;
typedef __attribute__((ext_vector_type(8))) __bf16 bf16x8;
typedef __attribute__((ext_vector_type(4))) float f32x4;
typedef __attribute__((ext_vector_type(4))) short s16x4;

#define S_LEN 2048
#define D_MODEL 2048
#define NHEADS 32
#define NKVH 8
#define HDIM 64
#define BATCH 2

__device__ __forceinline__ void async_cp16(const bf16* g, bf16* l) {
    __builtin_amdgcn_global_load_lds(
        (const __attribute__((address_space(1))) unsigned int*)g,
        (__attribute__((address_space(3))) unsigned int*)l, 16, 0, 0);
}

// ---------------- fused preprocessing: cvt fp32->bf16 + 4x weight transpose ----------------
// blocks [0,8192): cvt x -> X16 ; [8192,18432): W [K][N] fp32 -> Wt [N][K] bf16
__global__ void preproc(const float* __restrict__ x,
                        const float* __restrict__ Wq, const float* __restrict__ Wk,
                        const float* __restrict__ Wv, const float* __restrict__ Wo,
                        bf16* __restrict__ X16, bf16* __restrict__ WqT, bf16* __restrict__ WkT,
                        bf16* __restrict__ WvT, bf16* __restrict__ WoT) {
    __shared__ float tile[32][33];
    const int tid = threadIdx.x;
    int bid = blockIdx.x;
    if (bid < 8192) {
        int i = bid * 256 + tid;
        float4 f = ((const float4*)x)[i];
        union { bf16 h[4]; uint2 u; } t;
        t.h[0] = (bf16)f.x; t.h[1] = (bf16)f.y; t.h[2] = (bf16)f.z; t.h[3] = (bf16)f.w;
        ((uint2*)X16)[i] = t.u;
        return;
    }
    int l = bid - 8192;
    const float* W; bf16* Wt; int N, bx, by;
    const int K = 2048;
    if (l < 4096)      {            W = Wq; Wt = WqT; N = 2048; bx = l & 63; by = l >> 6; }
    else if (l < 5120) { l -= 4096; W = Wk; Wt = WkT; N = 512;  bx = l & 15; by = l >> 4; }
    else if (l < 6144) { l -= 5120; W = Wv; Wt = WvT; N = 512;  bx = l & 15; by = l >> 4; }
    else               { l -= 6144; W = Wo; Wt = WoT; N = 2048; bx = l & 63; by = l >> 6; }
    const int kt = by * 32, nt = bx * 32;
    const int tx = tid & 31, ty = tid >> 5;
    #pragma unroll
    for (int i = 0; i < 32; i += 8)
        tile[ty + i][tx] = W[(size_t)(kt + ty + i) * N + nt + tx];
    __syncthreads();
    #pragma unroll
    for (int i = 0; i < 32; i += 8)
        Wt[(size_t)(nt + ty + i) * K + kt + tx] = (bf16)tile[tx][ty + i];
}

// ---------------- GEMM (m97 staging, BK=64, 128x128 tile): C[M][N] = A[M][K] * Bt[N][K]^T ----------------
template <bool OUT_BF16>
__global__ __launch_bounds__(256) void gemm_bt(const bf16* __restrict__ A,
                                               const bf16* __restrict__ Bt,
                                               void* __restrict__ Cv,
                                               int M, int N, int K) {
    __shared__ __align__(16) bf16 As[128 * 64];
    __shared__ __align__(16) bf16 Bs[128 * 64];

    const int tid  = threadIdx.x;
    const int wave = tid >> 6;
    const int lane = tid & 63;
    const int l16  = lane & 15;
    const int quad = lane >> 4;
    const int wrow = (wave >> 1) * 64;
    const int wcol = (wave & 1) * 64;
    const int m0 = blockIdx.y * 128;
    const int n0 = blockIdx.x * 128;

    const int krow = lane >> 3;
    const int kc   = (lane & 7) ^ krow;
    const bf16* gA = A  + (size_t)(m0 + wave * 32 + krow) * K + kc * 8;
    const bf16* gB = Bt + (size_t)(n0 + wave * 32 + krow) * K + kc * 8;
    bf16* lA = &As[wave * 2048];
    bf16* lB = &Bs[wave * 2048];
    const size_t rstep = (size_t)8 * K;

    const int sw = l16 & 7;

    f32x4 acc[4][4];
    #pragma unroll
    for (int mi = 0; mi < 4; ++mi)
        #pragma unroll
        for (int ni = 0; ni < 4; ++ni)
            acc[mi][ni] = (f32x4){0.f, 0.f, 0.f, 0.f};

    for (int k0 = 0; k0 < K; k0 += 64) {
        __syncthreads();
        async_cp16(gA,             lA);
        async_cp16(gA +     rstep, lA + 512);
        async_cp16(gA + 2 * rstep, lA + 1024);
        async_cp16(gA + 3 * rstep, lA + 1536);
        async_cp16(gB,             lB);
        async_cp16(gB +     rstep, lB + 512);
        async_cp16(gB + 2 * rstep, lB + 1024);
        async_cp16(gB + 3 * rstep, lB + 1536);
        gA += 64; gB += 64;
        __syncthreads();

        #pragma unroll
        for (int kk = 0; kk < 2; ++kk) {
            bf16x8 af[4], bfr[4];
            #pragma unroll
            for (int mi = 0; mi < 4; ++mi)
                af[mi] = *(const bf16x8*)&As[(wrow + mi * 16 + l16) * 64 + (((kk * 4 + quad) ^ sw) * 8)];
            #pragma unroll
            for (int ni = 0; ni < 4; ++ni)
                bfr[ni] = *(const bf16x8*)&Bs[(wcol + ni * 16 + l16) * 64 + (((kk * 4 + quad) ^ sw) * 8)];
            #pragma unroll
            for (int mi = 0; mi < 4; ++mi)
                #pragma unroll
                for (int ni = 0; ni < 4; ++ni)
                    acc[mi][ni] = __builtin_amdgcn_mfma_f32_16x16x32_bf16(af[mi], bfr[ni], acc[mi][ni], 0, 0, 0);
        }
    }

    #pragma unroll
    for (int mi = 0; mi < 4; ++mi) {
        #pragma unroll
        for (int ni = 0; ni < 4; ++ni) {
            #pragma unroll
            for (int r = 0; r < 4; ++r) {
                size_t row = (size_t)(m0 + wrow + mi * 16 + quad * 4 + r);
                size_t col = (size_t)(n0 + wcol + ni * 16 + l16);
                if (OUT_BF16) ((bf16*)Cv)[row * N + col] = (bf16)acc[mi][ni][r];
                else          ((float*)Cv)[row * N + col] = acc[mi][ni][r];
            }
        }
    }
}

// ---------------- QKV GEMM 256x256 with FUSED RoPE epilogue ----------------
// [4096][2048] x [3072][2048]^T. Each wave's 64-col slice = one head's dims;
// RoPE pair (j, j+32) = (acc[mi][ni][r], acc[mi][ni+2][r]) - same lane. Q/K get
// roped in fp32 and written straight to Qr/Kr (Q scaled 0.125*log2e for exp2-domain
// attn); V cols written to QKV for transpose_v. Kills the rope half of rope_tv.
#define BUF1 16384

#define VMW(n) asm volatile("s_waitcnt vmcnt(" #n ")" ::: "memory")
#define BAR __builtin_amdgcn_s_barrier()

#define STAGE_A0(BUFOFF) do { \
    async_cp16(pa00, As + (BUFOFF) + la00); \
    async_cp16(pa01, As + (BUFOFF) + la01); \
    pa00 += 64; pa01 += 64; } while (0)
#define STAGE_A1(BUFOFF) do { \
    async_cp16(pa10, As + (BUFOFF) + la10); \
    async_cp16(pa11, As + (BUFOFF) + la11); \
    pa10 += 64; pa11 += 64; } while (0)
#define STAGE_B0(BUFOFF) do { \
    async_cp16(pb00, Bs + (BUFOFF) + lb00); \
    async_cp16(pb01, Bs + (BUFOFF) + lb01); \
    pb00 += 64; pb01 += 64; } while (0)
#define STAGE_B1(BUFOFF) do { \
    async_cp16(pb10, Bs + (BUFOFF) + lb10); \
    async_cp16(pb11, Bs + (BUFOFF) + lb11); \
    pb10 += 64; pb11 += 64; } while (0)

#define READ_A(QM, BUFOFF) do { \
    _Pragma("unroll") \
    for (int m_ = 0; m_ < 4; ++m_) { \
        const int row_ = wr * 128 + (QM) * 64 + m_ * 16 + l16; \
        af[m_][0] = *(const bf16x8*)&As[(BUFOFF) + row_ * 64 + ((quad ^ sw8) * 8)]; \
        af[m_][1] = *(const bf16x8*)&As[(BUFOFF) + row_ * 64 + (((4 + quad) ^ sw8) * 8)]; \
    } } while (0)

#define READ_B(QN, BUFOFF, BV) do { \
    _Pragma("unroll") \
    for (int n_ = 0; n_ < 2; ++n_) { \
        const int row_ = wc * 64 + (QN) * 32 + n_ * 16 + l16; \
        BV[n_][0] = *(const bf16x8*)&Bs[(BUFOFF) + row_ * 64 + ((quad ^ sw8) * 8)]; \
        BV[n_][1] = *(const bf16x8*)&Bs[(BUFOFF) + row_ * 64 + (((4 + quad) ^ sw8) * 8)]; \
    } } while (0)

#define MFMA_Q(QM, QN, BV) do { \
    _Pragma("unroll") \
    for (int kk_ = 0; kk_ < 2; ++kk_) \
        _Pragma("unroll") \
        for (int m_ = 0; m_ < 4; ++m_) \
            _Pragma("unroll") \
            for (int n_ = 0; n_ < 2; ++n_) \
                acc[(QM) * 4 + m_][(QN) * 2 + n_] = __builtin_amdgcn_mfma_f32_16x16x32_bf16( \
                    af[m_][kk_], BV[n_][kk_], acc[(QM) * 4 + m_][(QN) * 2 + n_], 0, 0, 0); \
    } while (0)

#define SYNCM(QM, QN, BV) do { \
    BAR; \
    __builtin_amdgcn_s_setprio(1); \
    MFMA_Q(QM, QN, BV); \
    __builtin_amdgcn_s_setprio(0); } while (0)

#define TILE_S(CUR) do { \
    READ_A(0, CUR); READ_B(0, CUR, bfr0);             SYNCM(0, 0, bfr0); BAR; \
    STAGE_A0(CUR); STAGE_B0(CUR); READ_B(1, CUR, bfr1); SYNCM(0, 1, bfr1); BAR; \
    STAGE_B1(CUR); READ_A(1, CUR);                    SYNCM(1, 0, bfr0); BAR; \
    STAGE_A1(CUR);                                    SYNCM(1, 1, bfr1); VMW(8); BAR; } while (0)

#define TILE_N(CUR, W) do { \
    READ_A(0, CUR); READ_B(0, CUR, bfr0); SYNCM(0, 0, bfr0); BAR; \
    READ_B(1, CUR, bfr1);                 SYNCM(0, 1, bfr1); BAR; \
    READ_A(1, CUR);                       SYNCM(1, 0, bfr0); BAR; \
                                          SYNCM(1, 1, bfr1); W; BAR; } while (0)

__global__ __launch_bounds__(512, 2) void gemm_qkv_rope(const bf16* __restrict__ A,
                                                        const bf16* __restrict__ Bt,
                                                        bf16* __restrict__ QKV,
                                                        bf16* __restrict__ Qr,
                                                        bf16* __restrict__ Kr) {
    const int N = 3072, K = 2048;
    __shared__ __align__(16) bf16 As[2 * 256 * 64];
    __shared__ __align__(16) bf16 Bs[2 * 256 * 64];

    const int tid  = threadIdx.x;
    const int w    = tid >> 6;
    const int lane = tid & 63;
    const int l16  = lane & 15;
    const int quad = lane >> 4;
    const int sw8  = l16 & 7;
    const int wr   = w >> 2;
    const int wc   = w & 3;

    const int nbx  = N >> 8;
    const int nwg  = gridDim.x;
    const int orig = blockIdx.x;
    const int wg   = (orig & 7) * (nwg >> 3) + (orig >> 3);
    const int n0   = (wg % nbx) * 256;
    const int m0   = (wg / nbx) * 256;

    const int krow = lane >> 3;
    const int kc   = (lane & 7) ^ krow;

    const bf16* pa00 = A + (size_t)(m0 +   0 + w * 8 + krow) * K + kc * 8;
    const bf16* pa01 = A + (size_t)(m0 + 128 + w * 8 + krow) * K + kc * 8;
    const bf16* pa10 = A + (size_t)(m0 +  64 + w * 8 + krow) * K + kc * 8;
    const bf16* pa11 = A + (size_t)(m0 + 192 + w * 8 + krow) * K + kc * 8;
    const int brow0 = (w >> 2) * 64 + (w & 3) * 8 + krow;
    const bf16* pb00 = Bt + (size_t)(n0 +       brow0) * K + kc * 8;
    const bf16* pb01 = Bt + (size_t)(n0 + 128 + brow0) * K + kc * 8;
    const bf16* pb10 = Bt + (size_t)(n0 +  32 + brow0) * K + kc * 8;
    const bf16* pb11 = Bt + (size_t)(n0 + 160 + brow0) * K + kc * 8;

    const int la00 = w * 512;
    const int la01 = 8192 + w * 512;
    const int la10 = 4096 + w * 512;
    const int la11 = 12288 + w * 512;
    const int lbb  = ((w >> 2) * 64 + (w & 3) * 8) * 64;
    const int lb00 = lbb;
    const int lb01 = 8192 + lbb;
    const int lb10 = 2048 + lbb;
    const int lb11 = 10240 + lbb;

    f32x4 acc[8][4];
    #pragma unroll
    for (int i = 0; i < 8; ++i)
        #pragma unroll
        for (int j = 0; j < 4; ++j) acc[i][j] = (f32x4){0.f, 0.f, 0.f, 0.f};

    bf16x8 af[4][2];
    bf16x8 bfr0[2][2];
    bf16x8 bfr1[2][2];

    STAGE_A0(0); STAGE_B0(0); STAGE_B1(0); STAGE_A1(0);
    STAGE_A0(BUF1); STAGE_B0(BUF1); STAGE_B1(BUF1); STAGE_A1(BUF1);
    VMW(8);
    BAR;

    const int NITER = K >> 6;
    for (int it = 0; it < (NITER - 2) >> 1; ++it) {
        TILE_S(0);
        TILE_S(BUF1);
    }
    TILE_N(0, VMW(0));
    TILE_N(BUF1, );

    // ---- epilogue: fused RoPE for Q/K cols, plain store for V cols ----
    const float LC = 0.28782313662425572f;       // ln(10000)/32
    const float QS = 0.18033688011112042f;       // 0.125 * log2(e)
    const int c0 = n0 + wc * 64;                 // wave's 64-col slice = one head
    const int rbase = m0 + wr * 128;

    if (c0 < 2560) {
        const bool isQ = c0 < 2048;
        const float scale = isQ ? QS : 1.0f;
        const int hh = isQ ? (c0 >> 6) : ((c0 - 2048) >> 6);
        const int HN = isQ ? NHEADS : NKVH;
        bf16* const base = isQ ? Qr : Kr;
        const float f0 = __expf(-(float)(l16) * LC);        // freq for jj = l16      (ni=0)
        const float f1 = __expf(-(float)(l16 + 16) * LC);   // freq for jj = l16 + 16 (ni=1)
        #pragma unroll
        for (int mi = 0; mi < 8; ++mi) {
            #pragma unroll
            for (int r = 0; r < 4; ++r) {
                int row = rbase + mi * 16 + quad * 4 + r;
                int bb = row >> 11, s = row & 2047;
                bf16* dst = base + (((size_t)(bb * HN + hh) * S_LEN + s) << 6);
                float sn0, cs0, sn1, cs1;
                sincosf((float)s * f0, &sn0, &cs0);
                sincosf((float)s * f1, &sn1, &cs1);
                float x10 = acc[mi][0][r], x20 = acc[mi][2][r];
                float x11 = acc[mi][1][r], x21 = acc[mi][3][r];
                dst[l16]      = (bf16)((x10 * cs0 - x20 * sn0) * scale);
                dst[l16 + 32] = (bf16)((x20 * cs0 + x10 * sn0) * scale);
                dst[l16 + 16] = (bf16)((x11 * cs1 - x21 * sn1) * scale);
                dst[l16 + 48] = (bf16)((x21 * cs1 + x11 * sn1) * scale);
            }
        }
    } else {
        #pragma unroll
        for (int mi = 0; mi < 8; ++mi)
            #pragma unroll
            for (int ni = 0; ni < 4; ++ni)
                #pragma unroll
                for (int r = 0; r < 4; ++r) {
                    size_t row = (size_t)(rbase + mi * 16 + quad * 4 + r);
                    QKV[row * 3072 + c0 + ni * 16 + l16] = (bf16)acc[mi][ni][r];
                }
    }
}

// ---------------- V slice of QKV -> Vt [b*8+kvh][d][s] bf16 ----------------
__global__ void transpose_v(const bf16* __restrict__ QKV, bf16* __restrict__ Vt) {
    __shared__ bf16 tl[32][33];
    int z = blockIdx.z;               // b*8+kvh
    int s0 = blockIdx.x * 32, d0 = blockIdx.y * 32;
    int bb = z >> 3, hh = z & 7;
    int tx = threadIdx.x, ty = threadIdx.y;
    #pragma unroll
    for (int i = 0; i < 32; i += 8)
        tl[ty + i][tx] = QKV[((size_t)(bb * S_LEN + s0 + ty + i)) * 3072 + 2560 + hh * 64 + d0 + tx];
    __syncthreads();
    #pragma unroll
    for (int i = 0; i < 32; i += 8)
        Vt[((size_t)z * 64 + d0 + ty + i) * S_LEN + s0 + tx] = tl[tx][ty + i];
}

// ---------------- Flash attention (causal GQA, S^T trick, exp2-domain online softmax) ----------------
// Exact R6 structure: measured 66.4us, 84 VGPR, bounds(256,3). Scalar l accumulation,
// per-tile rescale. Softmax in exp2 domain (Q pre-scaled by 0.125*log2e).
__global__ __launch_bounds__(256, 3) void attn_kernel(const bf16* __restrict__ Q,
                                                      const bf16* __restrict__ K,
                                                      const bf16* __restrict__ Vt,
                                                      bf16* __restrict__ Ctx) {
    __shared__ __align__(16) bf16 KsL[128 * 64];   // [key][dim], swizzled 16B chunks
    __shared__ __align__(16) bf16 VtL[64 * 128];   // [dim][key], swizzled 16B chunks

    static const signed char QTAB[16] = {15,14,13,12, 10,11,8,9, 5,4,7,6, 0,1,2,3};
    const int bx = blockIdx.x;
    const int qt = QTAB[((bx >> 8) << 2) | ((bx >> 6) & 3)];
    const int bh = bx & 63;
    const int b  = bh >> 5;
    const int h  = bh & 31;
    const int kvh = h >> 2;
    const int tid = threadIdx.x;
    const int wave = tid >> 6;
    const int lane = tid & 63;
    const int l16  = lane & 15;
    const int quad = lane >> 4;

    const bf16* Qb = Q  + ((size_t)(b * NHEADS + h)) * S_LEN * HDIM;
    const bf16* Kb = K  + ((size_t)(b * NKVH + kvh)) * S_LEN * HDIM;
    const bf16* Vb = Vt + ((size_t)(b * NKVH + kvh)) * HDIM * S_LEN;

    const int q0 = qt * 128;

    bf16x8 aq[2][2];
    #pragma unroll
    for (int qf = 0; qf < 2; ++qf)
        #pragma unroll
        for (int ks = 0; ks < 2; ++ks)
            aq[qf][ks] = *(const bf16x8*)(Qb + (size_t)(q0 + wave * 32 + qf * 16 + l16) * HDIM + ks * 32 + quad * 8);

    f32x4 O[2][4];
    float M0 = -1e30f, M1 = -1e30f;   // running max (log2 domain), q = l16 layout
    float l0 = 0.f, l1 = 0.f;         // running sums, q = l16 layout
    #pragma unroll
    for (int qf = 0; qf < 2; ++qf)
        #pragma unroll
        for (int df = 0; df < 4; ++df) O[qf][df] = (f32x4){0.f,0.f,0.f,0.f};

    const int krow = lane >> 3, kslot = lane & 7;
    const int kc   = kslot ^ (krow & 7);
    const int vslot = lane & 15, vsub = lane >> 4;

    #pragma unroll 1
    for (int kt = 0; kt <= qt; ++kt) {
        const int k0 = kt * 128;
        __syncthreads();
        #pragma unroll
        for (int j = 0; j < 4; ++j) {
            int rbase = (wave * 4 + j) * 8;                 // K rows
            async_cp16(Kb + (size_t)(k0 + rbase + krow) * HDIM + kc * 8, &KsL[rbase * 64]);
            int d0 = (wave * 4 + j) * 4;                    // V rows (dims)
            int vrow = d0 + vsub;
            int vc = vslot ^ (vrow & 15);
            async_cp16(Vb + (size_t)vrow * S_LEN + k0 + vc * 8, &VtL[d0 * 128]);
        }
        __syncthreads();

        // ---- S^T: all 8 kf tiles (rows=keys, cols=q) ----
        f32x4 sc[2][8];
        #pragma unroll
        for (int kf = 0; kf < 8; ++kf) {
            sc[0][kf] = (f32x4){0.f,0.f,0.f,0.f};
            sc[1][kf] = (f32x4){0.f,0.f,0.f,0.f};
            #pragma unroll
            for (int ks = 0; ks < 2; ++ks) {
                bf16x8 bk = *(const bf16x8*)&KsL[(kf * 16 + l16) * 64 + (((ks * 4 + quad) ^ (l16 & 7)) * 8)];
                sc[0][kf] = __builtin_amdgcn_mfma_f32_16x16x32_bf16(bk, aq[0][ks], sc[0][kf], 0, 0, 0);
                sc[1][kf] = __builtin_amdgcn_mfma_f32_16x16x32_bf16(bk, aq[1][ks], sc[1][kf], 0, 0, 0);
            }
        }

        if (kt == qt) {  // diagonal: causal mask (tile-local, k0==q0)
            #pragma unroll
            for (int kf = 0; kf < 8; ++kf)
                #pragma unroll
                for (int r = 0; r < 4; ++r) {
                    int key = kf * 16 + quad * 4 + r;
                    int qi0 = wave * 32 + l16;
                    if (key > qi0)      sc[0][kf][r] = -1e30f;
                    if (key > qi0 + 16) sc[1][kf][r] = -1e30f;
                }
        }

        // ---- tile max per q (l16 layout): per-lane max + 2 shfl_xor across quads ----
        float mx0 = sc[0][0][0], mx1 = sc[1][0][0];
        #pragma unroll
        for (int kf = 0; kf < 8; ++kf)
            #pragma unroll
            for (int r = 0; r < 4; ++r) {
                mx0 = fmaxf(mx0, sc[0][kf][r]);
                mx1 = fmaxf(mx1, sc[1][kf][r]);
            }
        mx0 = fmaxf(mx0, __shfl_xor(mx0, 16)); mx0 = fmaxf(mx0, __shfl_xor(mx0, 32));
        mx1 = fmaxf(mx1, __shfl_xor(mx1, 16)); mx1 = fmaxf(mx1, __shfl_xor(mx1, 32));

        float Mn0 = fmaxf(M0, mx0), Mn1 = fmaxf(M1, mx1);
        float a0 = __builtin_amdgcn_exp2f(M0 - Mn0);
        float a1 = __builtin_amdgcn_exp2f(M1 - Mn1);
        M0 = Mn0; M1 = Mn1;
        l0 *= a0; l1 *= a1;

        // ---- O rescale: alpha redistributed to q=quad*4+r layout ----
        #pragma unroll
        for (int r = 0; r < 4; ++r) {
            float aO0 = __shfl(a0, quad * 4 + r);
            float aO1 = __shfl(a1, quad * 4 + r);
            #pragma unroll
            for (int df = 0; df < 4; ++df) {
                O[0][df][r] *= aO0;
                O[1][df][r] *= aO1;
            }
        }

        // ---- P = exp2(S - M), accumulate l ----
        #pragma unroll
        for (int kf = 0; kf < 8; ++kf)
            #pragma unroll
            for (int r = 0; r < 4; ++r) {
                float e0 = __builtin_amdgcn_exp2f(sc[0][kf][r] - M0); sc[0][kf][r] = e0; l0 += e0;
                float e1 = __builtin_amdgcn_exp2f(sc[1][kf][r] - M1); sc[1][kf][r] = e1; l1 += e1;
            }

        // ---- O += P V : P direct from regs (A-frag of 16x16x16), V b64 from VtL ----
        #pragma unroll
        for (int kf = 0; kf < 8; ++kf) {
            union { bf16 hh[4]; s16x4 s4; } p0, p1;
            #pragma unroll
            for (int r = 0; r < 4; ++r) {
                p0.hh[r] = (bf16)sc[0][kf][r];
                p1.hh[r] = (bf16)sc[1][kf][r];
            }
            #pragma unroll
            for (int df = 0; df < 4; ++df) {
                s16x4 bv = *(const s16x4*)&VtL[(df * 16 + l16) * 128 +
                                               (((kf * 2 + (quad >> 1)) ^ l16) * 8) + (quad & 1) * 4];
                O[0][df] = __builtin_amdgcn_mfma_f32_16x16x16bf16_1k(p0.s4, bv, O[0][df], 0, 0, 0);
                O[1][df] = __builtin_amdgcn_mfma_f32_16x16x16bf16_1k(p1.s4, bv, O[1][df], 0, 0, 0);
            }
        }
    }

    // ---- epilogue: reduce l over quads (q=l16 layout), redistribute to D-layout ----
    l0 += __shfl_xor(l0, 16); l0 += __shfl_xor(l0, 32);
    l1 += __shfl_xor(l1, 16); l1 += __shfl_xor(l1, 32);
    #pragma unroll
    for (int r = 0; r < 4; ++r) {
        float inv0 = 1.0f / __shfl(l0, quad * 4 + r);
        float inv1 = 1.0f / __shfl(l1, quad * 4 + r);
        size_t row0 = (size_t)b * S_LEN + q0 + wave * 32 + quad * 4 + r;
        bf16* dst0 = Ctx + row0 * D_MODEL + h * HDIM;
        bf16* dst1 = dst0 + (size_t)16 * D_MODEL;
        #pragma unroll
        for (int df = 0; df < 4; ++df) {
            dst0[df * 16 + l16] = (bf16)(O[0][df][r] * inv0);
            dst1[df * 16 + l16] = (bf16)(O[1][df][r] * inv1);
        }
    }
}

extern "C" void kernel_launch(void* const* d_in, const int* in_sizes, int n_in,
                              void* d_out, int out_size, void* d_ws, size_t ws_size,
                              hipStream_t stream) {
    const float* x  = (const float*)d_in[0];
    const float* Wq = (const float*)d_in[1];
    const float* Wk = (const float*)d_in[2];
    const float* Wv = (const float*)d_in[3];
    const float* Wo = (const float*)d_in[4];

    char* p = (char*)d_ws;
    bf16* X16 = (bf16*)p; p += (size_t)4096 * 2048 * 2;
    bf16* WqT = (bf16*)p; p += (size_t)2048 * 2048 * 2;   // WqT/WkT/WvT contiguous: fused N=3072
    bf16* WkT = (bf16*)p; p += (size_t)512 * 2048 * 2;
    bf16* WvT = (bf16*)p; p += (size_t)512 * 2048 * 2;
    bf16* WoT = (bf16*)p; p += (size_t)2048 * 2048 * 2;
    bf16* QKV = (bf16*)p; p += (size_t)4096 * 3072 * 2;
    bf16* Qr  = (bf16*)p; p += (size_t)4096 * 2048 * 2;
    bf16* Kr  = (bf16*)p; p += (size_t)4096 * 512 * 2;
    bf16* Vt  = (bf16*)p; p += (size_t)16 * 64 * 2048 * 2;
    bf16* Ctx = QKV;  // QKV dead after transpose_v

    // fused cvt + 4x weight transpose: 8192 + 4096 + 1024 + 1024 + 4096 = 18432 blocks
    preproc<<<18432, 256, 0, stream>>>(x, Wq, Wk, Wv, Wo, X16, WqT, WkT, WvT, WoT);

    // QKV projection with fused RoPE: writes Qr, Kr directly; V cols -> QKV
    gemm_qkv_rope<<<dim3(192), 512, 0, stream>>>(X16, WqT, QKV, Qr, Kr);

    // V transpose only (rope now fused into the GEMM epilogue)
    transpose_v<<<dim3(64, 2, 16), dim3(32, 8), 0, stream>>>(QKV, Vt);

    attn_kernel<<<1024, 256, 0, stream>>>(Qr, Kr, Vt, Ctx);

    // output projection: [4096][2048] x [2048][2048]^T -> [4096][2048] fp32, 512 blocks (2/CU)
    gemm_bt<false><<<dim3(16, 32), 256, 0, stream>>>(Ctx, WoT, d_out, 4096, 2048, 2048);
}

// Round 10
// 290.232 us; speedup vs baseline: 1.0705x; 1.0705x over previous
//
#include <hip/hip_runtime.h>

typedef __bf16 bf16;
typedef __attribute__((ext_vector_type(8))) __bf16 bf16x8;
typedef __attribute__((ext_vector_type(4))) float f32x4;
typedef __attribute__((ext_vector_type(4))) short s16x4;

#define S_LEN 2048
#define D_MODEL 2048
#define NHEADS 32
#define NKVH 8
#define HDIM 64
#define BATCH 2

__device__ __forceinline__ void async_cp16(const bf16* g, bf16* l) {
    __builtin_amdgcn_global_load_lds(
        (const __attribute__((address_space(1))) unsigned int*)g,
        (__attribute__((address_space(3))) unsigned int*)l, 16, 0, 0);
}

// ---------------- fused preprocessing: rope table + cvt fp32->bf16 + 4x weight transpose ----------------
// blocks [0,256): cos/sin table [2048][32] ; [256,8448): cvt x -> X16 ;
// [8448,18688): W [K][N] fp32 -> Wt [N][K] bf16
__global__ void preproc(const float* __restrict__ x,
                        const float* __restrict__ Wq, const float* __restrict__ Wk,
                        const float* __restrict__ Wv, const float* __restrict__ Wo,
                        bf16* __restrict__ X16, bf16* __restrict__ WqT, bf16* __restrict__ WkT,
                        bf16* __restrict__ WvT, bf16* __restrict__ WoT,
                        float2* __restrict__ CS) {
    __shared__ float tile[32][33];
    const int tid = threadIdx.x;
    int bid = blockIdx.x;
    if (bid < 256) {                 // rope table: ang = s * 10000^(-j/32)
        const float LC = 0.28782313662425572f;   // ln(10000)/32
        int idx = bid * 256 + tid;
        int s = idx >> 5, j = idx & 31;
        float ang = (float)s * __expf(-(float)j * LC);
        float sn, cs; sincosf(ang, &sn, &cs);
        CS[idx] = make_float2(cs, sn);
        return;
    }
    bid -= 256;
    if (bid < 8192) {
        int i = bid * 256 + tid;
        float4 f = ((const float4*)x)[i];
        union { bf16 h[4]; uint2 u; } t;
        t.h[0] = (bf16)f.x; t.h[1] = (bf16)f.y; t.h[2] = (bf16)f.z; t.h[3] = (bf16)f.w;
        ((uint2*)X16)[i] = t.u;
        return;
    }
    int l = bid - 8192;
    const float* W; bf16* Wt; int N, bx, by;
    const int K = 2048;
    if (l < 4096)      {            W = Wq; Wt = WqT; N = 2048; bx = l & 63; by = l >> 6; }
    else if (l < 5120) { l -= 4096; W = Wk; Wt = WkT; N = 512;  bx = l & 15; by = l >> 4; }
    else if (l < 6144) { l -= 5120; W = Wv; Wt = WvT; N = 512;  bx = l & 15; by = l >> 4; }
    else               { l -= 6144; W = Wo; Wt = WoT; N = 2048; bx = l & 63; by = l >> 6; }
    const int kt = by * 32, nt = bx * 32;
    const int tx = tid & 31, ty = tid >> 5;
    #pragma unroll
    for (int i = 0; i < 32; i += 8)
        tile[ty + i][tx] = W[(size_t)(kt + ty + i) * N + nt + tx];
    __syncthreads();
    #pragma unroll
    for (int i = 0; i < 32; i += 8)
        Wt[(size_t)(nt + ty + i) * K + kt + tx] = (bf16)tile[tx][ty + i];
}

// ---------------- GEMM (m97 staging, BK=64, 128x128 tile): C[M][N] = A[M][K] * Bt[N][K]^T ----------------
template <bool OUT_BF16>
__global__ __launch_bounds__(256) void gemm_bt(const bf16* __restrict__ A,
                                               const bf16* __restrict__ Bt,
                                               void* __restrict__ Cv,
                                               int M, int N, int K) {
    __shared__ __align__(16) bf16 As[128 * 64];
    __shared__ __align__(16) bf16 Bs[128 * 64];

    const int tid  = threadIdx.x;
    const int wave = tid >> 6;
    const int lane = tid & 63;
    const int l16  = lane & 15;
    const int quad = lane >> 4;
    const int wrow = (wave >> 1) * 64;
    const int wcol = (wave & 1) * 64;
    const int m0 = blockIdx.y * 128;
    const int n0 = blockIdx.x * 128;

    const int krow = lane >> 3;
    const int kc   = (lane & 7) ^ krow;
    const bf16* gA = A  + (size_t)(m0 + wave * 32 + krow) * K + kc * 8;
    const bf16* gB = Bt + (size_t)(n0 + wave * 32 + krow) * K + kc * 8;
    bf16* lA = &As[wave * 2048];
    bf16* lB = &Bs[wave * 2048];
    const size_t rstep = (size_t)8 * K;

    const int sw = l16 & 7;

    f32x4 acc[4][4];
    #pragma unroll
    for (int mi = 0; mi < 4; ++mi)
        #pragma unroll
        for (int ni = 0; ni < 4; ++ni)
            acc[mi][ni] = (f32x4){0.f, 0.f, 0.f, 0.f};

    for (int k0 = 0; k0 < K; k0 += 64) {
        __syncthreads();
        async_cp16(gA,             lA);
        async_cp16(gA +     rstep, lA + 512);
        async_cp16(gA + 2 * rstep, lA + 1024);
        async_cp16(gA + 3 * rstep, lA + 1536);
        async_cp16(gB,             lB);
        async_cp16(gB +     rstep, lB + 512);
        async_cp16(gB + 2 * rstep, lB + 1024);
        async_cp16(gB + 3 * rstep, lB + 1536);
        gA += 64; gB += 64;
        __syncthreads();

        #pragma unroll
        for (int kk = 0; kk < 2; ++kk) {
            bf16x8 af[4], bfr[4];
            #pragma unroll
            for (int mi = 0; mi < 4; ++mi)
                af[mi] = *(const bf16x8*)&As[(wrow + mi * 16 + l16) * 64 + (((kk * 4 + quad) ^ sw) * 8)];
            #pragma unroll
            for (int ni = 0; ni < 4; ++ni)
                bfr[ni] = *(const bf16x8*)&Bs[(wcol + ni * 16 + l16) * 64 + (((kk * 4 + quad) ^ sw) * 8)];
            #pragma unroll
            for (int mi = 0; mi < 4; ++mi)
                #pragma unroll
                for (int ni = 0; ni < 4; ++ni)
                    acc[mi][ni] = __builtin_amdgcn_mfma_f32_16x16x32_bf16(af[mi], bfr[ni], acc[mi][ni], 0, 0, 0);
        }
    }

    #pragma unroll
    for (int mi = 0; mi < 4; ++mi) {
        #pragma unroll
        for (int ni = 0; ni < 4; ++ni) {
            #pragma unroll
            for (int r = 0; r < 4; ++r) {
                size_t row = (size_t)(m0 + wrow + mi * 16 + quad * 4 + r);
                size_t col = (size_t)(n0 + wcol + ni * 16 + l16);
                if (OUT_BF16) ((bf16*)Cv)[row * N + col] = (bf16)acc[mi][ni][r];
                else          ((float*)Cv)[row * N + col] = acc[mi][ni][r];
            }
        }
    }
}

// ---------------- GEMM 256x256, BK=64, 8-wave (QKV shape: measured 69.5us @ grid 192) ----------------
#define BUF1 16384

#define VMW(n) asm volatile("s_waitcnt vmcnt(" #n ")" ::: "memory")
#define BAR __builtin_amdgcn_s_barrier()

#define STAGE_A0(BUFOFF) do { \
    async_cp16(pa00, As + (BUFOFF) + la00); \
    async_cp16(pa01, As + (BUFOFF) + la01); \
    pa00 += 64; pa01 += 64; } while (0)
#define STAGE_A1(BUFOFF) do { \
    async_cp16(pa10, As + (BUFOFF) + la10); \
    async_cp16(pa11, As + (BUFOFF) + la11); \
    pa10 += 64; pa11 += 64; } while (0)
#define STAGE_B0(BUFOFF) do { \
    async_cp16(pb00, Bs + (BUFOFF) + lb00); \
    async_cp16(pb01, Bs + (BUFOFF) + lb01); \
    pb00 += 64; pb01 += 64; } while (0)
#define STAGE_B1(BUFOFF) do { \
    async_cp16(pb10, Bs + (BUFOFF) + lb10); \
    async_cp16(pb11, Bs + (BUFOFF) + lb11); \
    pb10 += 64; pb11 += 64; } while (0)

#define READ_A(QM, BUFOFF) do { \
    _Pragma("unroll") \
    for (int m_ = 0; m_ < 4; ++m_) { \
        const int row_ = wr * 128 + (QM) * 64 + m_ * 16 + l16; \
        af[m_][0] = *(const bf16x8*)&As[(BUFOFF) + row_ * 64 + ((quad ^ sw8) * 8)]; \
        af[m_][1] = *(const bf16x8*)&As[(BUFOFF) + row_ * 64 + (((4 + quad) ^ sw8) * 8)]; \
    } } while (0)

#define READ_B(QN, BUFOFF, BV) do { \
    _Pragma("unroll") \
    for (int n_ = 0; n_ < 2; ++n_) { \
        const int row_ = wc * 64 + (QN) * 32 + n_ * 16 + l16; \
        BV[n_][0] = *(const bf16x8*)&Bs[(BUFOFF) + row_ * 64 + ((quad ^ sw8) * 8)]; \
        BV[n_][1] = *(const bf16x8*)&Bs[(BUFOFF) + row_ * 64 + (((4 + quad) ^ sw8) * 8)]; \
    } } while (0)

#define MFMA_Q(QM, QN, BV) do { \
    _Pragma("unroll") \
    for (int kk_ = 0; kk_ < 2; ++kk_) \
        _Pragma("unroll") \
        for (int m_ = 0; m_ < 4; ++m_) \
            _Pragma("unroll") \
            for (int n_ = 0; n_ < 2; ++n_) \
                acc[(QM) * 4 + m_][(QN) * 2 + n_] = __builtin_amdgcn_mfma_f32_16x16x32_bf16( \
                    af[m_][kk_], BV[n_][kk_], acc[(QM) * 4 + m_][(QN) * 2 + n_], 0, 0, 0); \
    } while (0)

#define SYNCM(QM, QN, BV) do { \
    BAR; \
    __builtin_amdgcn_s_setprio(1); \
    MFMA_Q(QM, QN, BV); \
    __builtin_amdgcn_s_setprio(0); } while (0)

#define TILE_S(CUR) do { \
    READ_A(0, CUR); READ_B(0, CUR, bfr0);             SYNCM(0, 0, bfr0); BAR; \
    STAGE_A0(CUR); STAGE_B0(CUR); READ_B(1, CUR, bfr1); SYNCM(0, 1, bfr1); BAR; \
    STAGE_B1(CUR); READ_A(1, CUR);                    SYNCM(1, 0, bfr0); BAR; \
    STAGE_A1(CUR);                                    SYNCM(1, 1, bfr1); VMW(8); BAR; } while (0)

#define TILE_N(CUR, W) do { \
    READ_A(0, CUR); READ_B(0, CUR, bfr0); SYNCM(0, 0, bfr0); BAR; \
    READ_B(1, CUR, bfr1);                 SYNCM(0, 1, bfr1); BAR; \
    READ_A(1, CUR);                       SYNCM(1, 0, bfr0); BAR; \
                                          SYNCM(1, 1, bfr1); W; BAR; } while (0)

template <bool OUT_BF16>
__global__ __launch_bounds__(512, 2) void gemm256(const bf16* __restrict__ A,
                                                  const bf16* __restrict__ Bt,
                                                  void* __restrict__ Cv,
                                                  int N, int K) {
    __shared__ __align__(16) bf16 As[2 * 256 * 64];
    __shared__ __align__(16) bf16 Bs[2 * 256 * 64];

    const int tid  = threadIdx.x;
    const int w    = tid >> 6;
    const int lane = tid & 63;
    const int l16  = lane & 15;
    const int quad = lane >> 4;
    const int sw8  = l16 & 7;
    const int wr   = w >> 2;
    const int wc   = w & 3;

    const int nbx  = N >> 8;
    const int nwg  = gridDim.x;
    const int orig = blockIdx.x;
    const int wg   = (orig & 7) * (nwg >> 3) + (orig >> 3);
    const int n0   = (wg % nbx) * 256;
    const int m0   = (wg / nbx) * 256;

    const int krow = lane >> 3;
    const int kc   = (lane & 7) ^ krow;

    const bf16* pa00 = A + (size_t)(m0 +   0 + w * 8 + krow) * K + kc * 8;
    const bf16* pa01 = A + (size_t)(m0 + 128 + w * 8 + krow) * K + kc * 8;
    const bf16* pa10 = A + (size_t)(m0 +  64 + w * 8 + krow) * K + kc * 8;
    const bf16* pa11 = A + (size_t)(m0 + 192 + w * 8 + krow) * K + kc * 8;
    const int brow0 = (w >> 2) * 64 + (w & 3) * 8 + krow;
    const bf16* pb00 = Bt + (size_t)(n0 +       brow0) * K + kc * 8;
    const bf16* pb01 = Bt + (size_t)(n0 + 128 + brow0) * K + kc * 8;
    const bf16* pb10 = Bt + (size_t)(n0 +  32 + brow0) * K + kc * 8;
    const bf16* pb11 = Bt + (size_t)(n0 + 160 + brow0) * K + kc * 8;

    const int la00 = w * 512;
    const int la01 = 8192 + w * 512;
    const int la10 = 4096 + w * 512;
    const int la11 = 12288 + w * 512;
    const int lbb  = ((w >> 2) * 64 + (w & 3) * 8) * 64;
    const int lb00 = lbb;
    const int lb01 = 8192 + lbb;
    const int lb10 = 2048 + lbb;
    const int lb11 = 10240 + lbb;

    f32x4 acc[8][4];
    #pragma unroll
    for (int i = 0; i < 8; ++i)
        #pragma unroll
        for (int j = 0; j < 4; ++j) acc[i][j] = (f32x4){0.f, 0.f, 0.f, 0.f};

    bf16x8 af[4][2];
    bf16x8 bfr0[2][2];
    bf16x8 bfr1[2][2];

    STAGE_A0(0); STAGE_B0(0); STAGE_B1(0); STAGE_A1(0);
    STAGE_A0(BUF1); STAGE_B0(BUF1); STAGE_B1(BUF1); STAGE_A1(BUF1);
    VMW(8);
    BAR;

    const int NITER = K >> 6;
    for (int it = 0; it < (NITER - 2) >> 1; ++it) {
        TILE_S(0);
        TILE_S(BUF1);
    }
    TILE_N(0, VMW(0));
    TILE_N(BUF1, );

    #pragma unroll
    for (int mi = 0; mi < 8; ++mi)
        #pragma unroll
        for (int ni = 0; ni < 4; ++ni)
            #pragma unroll
            for (int r = 0; r < 4; ++r) {
                size_t row = (size_t)(m0 + wr * 128 + mi * 16 + quad * 4 + r);
                size_t col = (size_t)(n0 + wc * 64 + ni * 16 + l16);
                if (OUT_BF16) ((bf16*)Cv)[row * N + col] = (bf16)acc[mi][ni][r];
                else          ((float*)Cv)[row * N + col] = acc[mi][ni][r];
            }
}

// ---------------- fused RoPE-relayout + V transpose (table-driven trig) ----------------
// blocks [0,20480): rope Q/K via CS table ; [20480,22528): V slice -> Vt [b*8+kvh][d][s]
// Q is scaled by (1/8)*log2(e): attention exp runs in exp2 domain.
__global__ void rope_tv(const bf16* __restrict__ QKV,
                        const float2* __restrict__ CS,
                        bf16* __restrict__ Qr, bf16* __restrict__ Kr,
                        bf16* __restrict__ Vt) {
    __shared__ bf16 tl[32][33];
    const int tid = threadIdx.x;
    const int bid = blockIdx.x;
    const float QS = 0.18033688011112042f;       // 0.125 * log2(e)
    if (bid < 20480) {
        const int QN = BATCH * S_LEN * NHEADS * 32;  // 4194304
        int idx = bid * 256 + tid;
        if (idx < QN) {
            int j = idx & 31, hh = (idx >> 5) & 31, s = (idx >> 10) & 2047, bb = idx >> 21;
            size_t src = ((size_t)(bb * S_LEN + s)) * 3072 + hh * HDIM + j;
            float x1 = (float)QKV[src], x2 = (float)QKV[src + 32];
            float2 cs2 = CS[(s << 5) + j];
            size_t dst = ((size_t)((bb * NHEADS + hh) * S_LEN + s)) * HDIM + j;
            Qr[dst]      = (bf16)((x1 * cs2.x - x2 * cs2.y) * QS);
            Qr[dst + 32] = (bf16)((x2 * cs2.x + x1 * cs2.y) * QS);
        } else {
            int t = idx - QN;
            int j = t & 31, hh = (t >> 5) & 7, s = (t >> 8) & 2047, bb = t >> 19;
            size_t src = ((size_t)(bb * S_LEN + s)) * 3072 + 2048 + hh * HDIM + j;
            float x1 = (float)QKV[src], x2 = (float)QKV[src + 32];
            float2 cs2 = CS[(s << 5) + j];
            size_t dst = ((size_t)((bb * NKVH + hh) * S_LEN + s)) * HDIM + j;
            Kr[dst]      = (bf16)(x1 * cs2.x - x2 * cs2.y);
            Kr[dst + 32] = (bf16)(x2 * cs2.x + x1 * cs2.y);
        }
        return;
    }
    int l = bid - 20480;                 // transpose_v: 64 x 2 x 16 blocks
    int s0 = (l & 63) * 32;
    int d0 = ((l >> 6) & 1) * 32;
    int z  = l >> 7;                     // b*8+kvh
    int bb = z >> 3, hh = z & 7;
    int tx = tid & 31, ty = tid >> 5;
    #pragma unroll
    for (int i = 0; i < 32; i += 8)
        tl[ty + i][tx] = QKV[((size_t)(bb * S_LEN + s0 + ty + i)) * 3072 + 2560 + hh * 64 + d0 + tx];
    __syncthreads();
    #pragma unroll
    for (int i = 0; i < 32; i += 8)
        Vt[((size_t)z * 64 + d0 + ty + i) * S_LEN + s0 + tx] = tl[tx][ty + i];
}

// ---------------- Flash attention (causal GQA, S^T trick, exp2-domain online softmax) ----------------
// Exact R6 structure: measured 66.4us, 84 VGPR, bounds(256,3). Scalar l accumulation,
// per-tile rescale. Softmax in exp2 domain (Q pre-scaled by 0.125*log2e).
__global__ __launch_bounds__(256, 3) void attn_kernel(const bf16* __restrict__ Q,
                                                      const bf16* __restrict__ K,
                                                      const bf16* __restrict__ Vt,
                                                      bf16* __restrict__ Ctx) {
    __shared__ __align__(16) bf16 KsL[128 * 64];   // [key][dim], swizzled 16B chunks
    __shared__ __align__(16) bf16 VtL[64 * 128];   // [dim][key], swizzled 16B chunks

    static const signed char QTAB[16] = {15,14,13,12, 10,11,8,9, 5,4,7,6, 0,1,2,3};
    const int bx = blockIdx.x;
    const int qt = QTAB[((bx >> 8) << 2) | ((bx >> 6) & 3)];
    const int bh = bx & 63;
    const int b  = bh >> 5;
    const int h  = bh & 31;
    const int kvh = h >> 2;
    const int tid = threadIdx.x;
    const int wave = tid >> 6;
    const int lane = tid & 63;
    const int l16  = lane & 15;
    const int quad = lane >> 4;

    const bf16* Qb = Q  + ((size_t)(b * NHEADS + h)) * S_LEN * HDIM;
    const bf16* Kb = K  + ((size_t)(b * NKVH + kvh)) * S_LEN * HDIM;
    const bf16* Vb = Vt + ((size_t)(b * NKVH + kvh)) * HDIM * S_LEN;

    const int q0 = qt * 128;

    bf16x8 aq[2][2];
    #pragma unroll
    for (int qf = 0; qf < 2; ++qf)
        #pragma unroll
        for (int ks = 0; ks < 2; ++ks)
            aq[qf][ks] = *(const bf16x8*)(Qb + (size_t)(q0 + wave * 32 + qf * 16 + l16) * HDIM + ks * 32 + quad * 8);

    f32x4 O[2][4];
    float M0 = -1e30f, M1 = -1e30f;   // running max (log2 domain), q = l16 layout
    float l0 = 0.f, l1 = 0.f;         // running sums, q = l16 layout
    #pragma unroll
    for (int qf = 0; qf < 2; ++qf)
        #pragma unroll
        for (int df = 0; df < 4; ++df) O[qf][df] = (f32x4){0.f,0.f,0.f,0.f};

    const int krow = lane >> 3, kslot = lane & 7;
    const int kc   = kslot ^ (krow & 7);
    const int vslot = lane & 15, vsub = lane >> 4;

    #pragma unroll 1
    for (int kt = 0; kt <= qt; ++kt) {
        const int k0 = kt * 128;
        __syncthreads();
        #pragma unroll
        for (int j = 0; j < 4; ++j) {
            int rbase = (wave * 4 + j) * 8;                 // K rows
            async_cp16(Kb + (size_t)(k0 + rbase + krow) * HDIM + kc * 8, &KsL[rbase * 64]);
            int d0 = (wave * 4 + j) * 4;                    // V rows (dims)
            int vrow = d0 + vsub;
            int vc = vslot ^ (vrow & 15);
            async_cp16(Vb + (size_t)vrow * S_LEN + k0 + vc * 8, &VtL[d0 * 128]);
        }
        __syncthreads();

        // ---- S^T: all 8 kf tiles (rows=keys, cols=q) ----
        f32x4 sc[2][8];
        #pragma unroll
        for (int kf = 0; kf < 8; ++kf) {
            sc[0][kf] = (f32x4){0.f,0.f,0.f,0.f};
            sc[1][kf] = (f32x4){0.f,0.f,0.f,0.f};
            #pragma unroll
            for (int ks = 0; ks < 2; ++ks) {
                bf16x8 bk = *(const bf16x8*)&KsL[(kf * 16 + l16) * 64 + (((ks * 4 + quad) ^ (l16 & 7)) * 8)];
                sc[0][kf] = __builtin_amdgcn_mfma_f32_16x16x32_bf16(bk, aq[0][ks], sc[0][kf], 0, 0, 0);
                sc[1][kf] = __builtin_amdgcn_mfma_f32_16x16x32_bf16(bk, aq[1][ks], sc[1][kf], 0, 0, 0);
            }
        }

        if (kt == qt) {  // diagonal: causal mask (tile-local, k0==q0)
            #pragma unroll
            for (int kf = 0; kf < 8; ++kf)
                #pragma unroll
                for (int r = 0; r < 4; ++r) {
                    int key = kf * 16 + quad * 4 + r;
                    int qi0 = wave * 32 + l16;
                    if (key > qi0)      sc[0][kf][r] = -1e30f;
                    if (key > qi0 + 16) sc[1][kf][r] = -1e30f;
                }
        }

        // ---- tile max per q (l16 layout): per-lane max + 2 shfl_xor across quads ----
        float mx0 = sc[0][0][0], mx1 = sc[1][0][0];
        #pragma unroll
        for (int kf = 0; kf < 8; ++kf)
            #pragma unroll
            for (int r = 0; r < 4; ++r) {
                mx0 = fmaxf(mx0, sc[0][kf][r]);
                mx1 = fmaxf(mx1, sc[1][kf][r]);
            }
        mx0 = fmaxf(mx0, __shfl_xor(mx0, 16)); mx0 = fmaxf(mx0, __shfl_xor(mx0, 32));
        mx1 = fmaxf(mx1, __shfl_xor(mx1, 16)); mx1 = fmaxf(mx1, __shfl_xor(mx1, 32));

        float Mn0 = fmaxf(M0, mx0), Mn1 = fmaxf(M1, mx1);
        float a0 = __builtin_amdgcn_exp2f(M0 - Mn0);
        float a1 = __builtin_amdgcn_exp2f(M1 - Mn1);
        M0 = Mn0; M1 = Mn1;
        l0 *= a0; l1 *= a1;

        // ---- O rescale: alpha redistributed to q=quad*4+r layout ----
        #pragma unroll
        for (int r = 0; r < 4; ++r) {
            float aO0 = __shfl(a0, quad * 4 + r);
            float aO1 = __shfl(a1, quad * 4 + r);
            #pragma unroll
            for (int df = 0; df < 4; ++df) {
                O[0][df][r] *= aO0;
                O[1][df][r] *= aO1;
            }
        }

        // ---- P = exp2(S - M), accumulate l ----
        #pragma unroll
        for (int kf = 0; kf < 8; ++kf)
            #pragma unroll
            for (int r = 0; r < 4; ++r) {
                float e0 = __builtin_amdgcn_exp2f(sc[0][kf][r] - M0); sc[0][kf][r] = e0; l0 += e0;
                float e1 = __builtin_amdgcn_exp2f(sc[1][kf][r] - M1); sc[1][kf][r] = e1; l1 += e1;
            }

        // ---- O += P V : P direct from regs (A-frag of 16x16x16), V b64 from VtL ----
        #pragma unroll
        for (int kf = 0; kf < 8; ++kf) {
            union { bf16 hh[4]; s16x4 s4; } p0, p1;
            #pragma unroll
            for (int r = 0; r < 4; ++r) {
                p0.hh[r] = (bf16)sc[0][kf][r];
                p1.hh[r] = (bf16)sc[1][kf][r];
            }
            #pragma unroll
            for (int df = 0; df < 4; ++df) {
                s16x4 bv = *(const s16x4*)&VtL[(df * 16 + l16) * 128 +
                                               (((kf * 2 + (quad >> 1)) ^ l16) * 8) + (quad & 1) * 4];
                O[0][df] = __builtin_amdgcn_mfma_f32_16x16x16bf16_1k(p0.s4, bv, O[0][df], 0, 0, 0);
                O[1][df] = __builtin_amdgcn_mfma_f32_16x16x16bf16_1k(p1.s4, bv, O[1][df], 0, 0, 0);
            }
        }
    }

    // ---- epilogue: reduce l over quads (q=l16 layout), redistribute to D-layout ----
    l0 += __shfl_xor(l0, 16); l0 += __shfl_xor(l0, 32);
    l1 += __shfl_xor(l1, 16); l1 += __shfl_xor(l1, 32);
    #pragma unroll
    for (int r = 0; r < 4; ++r) {
        float inv0 = 1.0f / __shfl(l0, quad * 4 + r);
        float inv1 = 1.0f / __shfl(l1, quad * 4 + r);
        size_t row0 = (size_t)b * S_LEN + q0 + wave * 32 + quad * 4 + r;
        bf16* dst0 = Ctx + row0 * D_MODEL + h * HDIM;
        bf16* dst1 = dst0 + (size_t)16 * D_MODEL;
        #pragma unroll
        for (int df = 0; df < 4; ++df) {
            dst0[df * 16 + l16] = (bf16)(O[0][df][r] * inv0);
            dst1[df * 16 + l16] = (bf16)(O[1][df][r] * inv1);
        }
    }
}

extern "C" void kernel_launch(void* const* d_in, const int* in_sizes, int n_in,
                              void* d_out, int out_size, void* d_ws, size_t ws_size,
                              hipStream_t stream) {
    const float* x  = (const float*)d_in[0];
    const float* Wq = (const float*)d_in[1];
    const float* Wk = (const float*)d_in[2];
    const float* Wv = (const float*)d_in[3];
    const float* Wo = (const float*)d_in[4];

    char* p = (char*)d_ws;
    bf16* X16 = (bf16*)p; p += (size_t)4096 * 2048 * 2;
    bf16* WqT = (bf16*)p; p += (size_t)2048 * 2048 * 2;   // WqT/WkT/WvT contiguous: fused N=3072
    bf16* WkT = (bf16*)p; p += (size_t)512 * 2048 * 2;
    bf16* WvT = (bf16*)p; p += (size_t)512 * 2048 * 2;
    bf16* WoT = (bf16*)p; p += (size_t)2048 * 2048 * 2;
    bf16* QKV = (bf16*)p; p += (size_t)4096 * 3072 * 2;
    bf16* Qr  = (bf16*)p; p += (size_t)4096 * 2048 * 2;
    bf16* Kr  = (bf16*)p; p += (size_t)4096 * 512 * 2;
    bf16* Vt  = (bf16*)p; p += (size_t)16 * 64 * 2048 * 2;
    float2* CS = (float2*)p; p += (size_t)2048 * 32 * 8;  // rope cos/sin table, 512 KB
    bf16* Ctx = QKV;  // QKV dead after rope_tv

    // fused rope-table + cvt + 4x weight transpose: 256 + 8192 + 10240 = 18688 blocks
    preproc<<<18688, 256, 0, stream>>>(x, Wq, Wk, Wv, Wo, X16, WqT, WkT, WvT, WoT, CS);

    // fused QKV projection: [4096][2048] x [3072][2048]^T -> [4096][3072], 192 blocks
    gemm256<true><<<dim3(192), 512, 0, stream>>>(X16, WqT, (void*)QKV, 3072, 2048);

    // fused rope relayout (table-driven, 20480 blocks) + V transpose (2048 blocks)
    rope_tv<<<22528, 256, 0, stream>>>(QKV, CS, Qr, Kr, Vt);

    attn_kernel<<<1024, 256, 0, stream>>>(Qr, Kr, Vt, Ctx);

    // output projection: [4096][2048] x [2048][2048]^T -> [4096][2048] fp32, 512 blocks (2/CU)
    gemm_bt<false><<<dim3(16, 32), 256, 0, stream>>>(Ctx, WoT, d_out, 4096, 2048, 2048);
}